// Round 1
// baseline (185.173 us; speedup 1.0000x reference)
//
#include <hip/hip_runtime.h>
#include <hip/hip_bf16.h>

// ---------------------------------------------------------------------------
// GNN action-value net, MI355X. Round 12: occupancy doubling.
//  * graph_kernel now 512 threads (8 waves: 4 row-groups x 2 col-halves),
//    LDS 40.2KB -> still 4 blocks/CU => 32 waves/CU (was 16). The kernel is
//    latency-bound (MfmaUtil 6.5 / VALU 22 / occ 36), so TLP is the lever.
//  * Pf attention matrix XOR-swizzled at float4 granularity: kills the
//    16-way bank conflict on the agg1/agg2 A-frag preload (row stride 64
//    dwords == 0 mod 32), and spreads edge-atomic banks by d.
//  * E1 gather remapped: wave=16-feat block, lane=node -> conflict-free
//    lane-consecutive LDS writes; g_nt1 reads L1-resident.
//  * 12 barriers (col-split breaks own-wave row reuse for h1f/af; h2f load
//    hoisted into the free B8->B9 slot).
// Fragment maps (verified r5-r10): A[m][k]: m=lane&15, k=(lane>>4)*8+j;
// B[k][n]: n=lane&15, k=(lane>>4)*8+j; C/D: col=lane&15, row=(lane>>4)*4+reg.
// ---------------------------------------------------------------------------

#define NPG 64
#define EPG 1024
#define NEPG 256
#define B_GR 1024
#define E_TOT 1048576
#define EMB 64
#define HID 128
#define NOUT 101
#define OUT_PG 6721            // 1 + 64*101 + 256

typedef __attribute__((ext_vector_type(8))) short bf16x8;
typedef __attribute__((ext_vector_type(4))) float f32x4;
typedef unsigned short ushort_t;

__device__ ushort_t g_nt1[100*HID];      // bf16 rows: node_tab @ c1_w
__device__ ushort_t g_c2w[HID*HID];      // frag-packed bf16
__device__ ushort_t g_nw1[HID*HID];
__device__ ushort_t g_ew1[HID*HID];
__device__ ushort_t g_nw2[HID*112];      // N padded 101 -> 112
__device__ float    g_sw1t[HID*HID];     // s_w1 transposed, f32
__device__ float    g_hs1[128], g_hd1[128];   // per-category attn scalars
__device__ float    g_he1[4], g_he2[4];

__device__ __forceinline__ ushort_t f2bf(float f) {
  unsigned u = __float_as_uint(f);
  return (ushort_t)((u + 0x7fffu + ((u >> 16) & 1u)) >> 16);
}
__device__ __forceinline__ float bf2f(ushort_t h) {
  return __uint_as_float(((unsigned)h) << 16);
}
__device__ __forceinline__ unsigned pk2(float a, float b) {
  __hip_bfloat162 h = __float22bfloat162_rn(make_float2(a, b));
  unsigned r; __builtin_memcpy(&r, &h, 4); return r;
}
__device__ __forceinline__ bf16x8 pk8(float4 v0, float4 v1) {
  union { bf16x8 v; unsigned u[4]; } o;
  o.u[0] = pk2(v0.x, v0.y); o.u[1] = pk2(v0.z, v0.w);
  o.u[2] = pk2(v1.x, v1.y); o.u[3] = pk2(v1.z, v1.w);
  return o.v;
}
// Pf swizzle: float4-slot index XORed with row&15. Bijective per row;
// makes the agg preload (lanes read same col-chunk of 16 different rows)
// hit all 8 bank groups uniformly.
__device__ __forceinline__ int pf_idx(int d, int s) {
  return d*64 + ((((s >> 2) ^ d) & 15) << 2) + (s & 3);
}

// ---------------------------------------------------------------------------
// prep: 91 blocks. b0: logit consts. b1-50: nt1. b51: hs1/hd1.
// b52-75: c2w/nw1/ew1. b76-82: nw2. b83-90: sw1t.
__global__ void prep_kernel(
    const float* __restrict__ node_tab, const float* __restrict__ edge_tab,
    const float* __restrict__ c1_w,  const float* __restrict__ c1_we,
    const float* __restrict__ c1_as, const float* __restrict__ c1_ad,
    const float* __restrict__ c1_ae,
    const float* __restrict__ c2_w,  const float* __restrict__ c2_we,
    const float* __restrict__ c2_ae,
    const float* __restrict__ s_w1,  const float* __restrict__ n_w1,
    const float* __restrict__ n_w2,  const float* __restrict__ e_w1)
{
  const int b = blockIdx.x, tid = threadIdx.x;
  if (b == 0) {                       // per-edge-type logit constants
    __shared__ float v1[EMB], v2[EMB];
    if (tid < EMB) {
      float a = 0.f, d = 0.f;
      for (int j = 0; j < HID; ++j) {
        a = fmaf(c1_we[tid*HID + j], c1_ae[j], a);
        d = fmaf(c2_we[tid*HID + j], c2_ae[j], d);
      }
      v1[tid] = a; v2[tid] = d;
    }
    __syncthreads();
    if (tid < 4) {
      float a = 0.f, d = 0.f;
      for (int k = 0; k < EMB; ++k) {
        const float ev = edge_tab[tid*EMB + k];
        a = fmaf(ev, v1[k], a); d = fmaf(ev, v2[k], d);
      }
      g_he1[tid] = a; g_he2[tid] = d;
    }
    return;
  }
  if (b <= 50) {                      // nt1 = node_tab @ c1_w (100x128)
    const int idx = (b - 1) * 256 + tid;
    const int i = idx >> 7, j = idx & (HID - 1);
    float s = 0.f;
    #pragma unroll 8
    for (int k = 0; k < EMB; ++k) s = fmaf(node_tab[i*EMB + k], c1_w[k*HID + j], s);
    g_nt1[idx] = f2bf(s);
    return;
  }
  if (b == 51) {                      // per-category attention scalars
    __shared__ float vs[EMB], vd[EMB];
    if (tid < EMB) {
      float a = 0.f, d = 0.f;
      for (int j = 0; j < HID; ++j) {
        const float w = c1_w[tid*HID + j];
        a = fmaf(w, c1_as[j], a); d = fmaf(w, c1_ad[j], d);
      }
      vs[tid] = a; vd[tid] = d;
    }
    __syncthreads();
    if (tid < 128) {
      float a = 0.f, d = 0.f;
      if (tid < 100) {
        for (int k = 0; k < EMB; ++k) {
          const float xv = node_tab[tid*EMB + k];
          a = fmaf(xv, vs[k], a); d = fmaf(xv, vd[k], d);
        }
      }
      g_hs1[tid] = a; g_hd1[tid] = d;
    }
    return;
  }
  if (b <= 75) {                      // c2w / nw1 / ew1: 16384 each, 8 chunks
    const int grp = (b - 52) >> 3;
    const int chunk = (b - 52) & 7;
    const float* W = (grp == 0) ? c2_w : (grp == 1) ? n_w1 : e_w1;
    ushort_t* G = (grp == 0) ? g_c2w : (grp == 1) ? g_nw1 : g_ew1;
    const int base = chunk * 2048 + tid;
    #pragma unroll
    for (int it = 0; it < 8; ++it) {
      const int idx = base + it*256;
      const int j = idx & 7, l = (idx >> 3) & 63, r2 = idx >> 9;
      const int ks = r2 & 3, ct = r2 >> 2;
      const int row = ks*32 + (l >> 4)*8 + j;
      const int col = ct*16 + (l & 15);
      G[idx] = f2bf(W[row*HID + col]);
    }
    return;
  }
  if (b <= 82) {                      // nw2: 14336, 7 chunks
    const int base = (b - 76) * 2048 + tid;
    #pragma unroll
    for (int it = 0; it < 8; ++it) {
      const int idx = base + it*256;
      const int j = idx & 7, l = (idx >> 3) & 63, r2 = idx >> 9;
      const int ks = r2 & 3, ct = r2 >> 2;
      const int row = ks*32 + (l >> 4)*8 + j;
      const int col = ct*16 + (l & 15);
      g_nw2[idx] = (col < NOUT) ? f2bf(n_w2[row*NOUT + col]) : (ushort_t)0;
    }
    return;
  }
  {                                   // sw1t: 16384, 8 chunks
    const int base = (b - 83) * 2048 + tid;
    #pragma unroll
    for (int it = 0; it < 8; ++it) {
      const int idx = base + it*256;
      g_sw1t[idx] = s_w1[(idx & 127)*HID + (idx >> 7)];
    }
  }
}

// ---------------------------------------------------------------------------
// LDS map (bytes). Region R overlays Pf(64x64 f32, swizzled) / Hr(64x136 us).
#define S_HC   0        // 128x72 ushort feat-major; reused as a1b 64x136 rows
#define S_R    18432    // max(Pf 16384, Hr 17408)
#define S_PART 35840    // 512 f32 (stop partials, 4 k-chunks)
#define S_NS   37888    // 64 f32
#define S_ND   38144    // 64 f32
#define S_GP   38400    // 128 f32 (pool)
#define S_EBW  38912    // 256 f32: e_b1[0..127] | e_w2[0..127]
#define S_HCC  39936    // 8 f32
#define S_XS   39968    // 64 int
#define S_TOT  40224    // 4 x 40448(rounded) = 161792 <= 163840 -> 4 blk/CU

__global__ __launch_bounds__(512, 8) void graph_kernel(
    const float* __restrict__ c1_b,
    const float* __restrict__ c2_as, const float* __restrict__ c2_ad,
    const float* __restrict__ c2_b,
    const float* __restrict__ s_b1,  const float* __restrict__ s_w2,
    const float* __restrict__ s_b2,
    const float* __restrict__ n_b1,  const float* __restrict__ n_b2,
    const float* __restrict__ e_b1,  const float* __restrict__ e_w2,
    const float* __restrict__ e_b2,
    const int* __restrict__ x,  const int* __restrict__ ei,
    const int* __restrict__ ea, const int* __restrict__ nedg,
    float* __restrict__ out)
{
  const int tid = threadIdx.x;
  const int gid = blockIdx.x;
  const int nb = gid * NPG;
  const int lane = tid & 63;
  const int wv = tid >> 6;         // 0..7
  const int wr = wv & 3;           // row-group
  const int ch = wv >> 2;          // col-half (ct in [ch*4, ch*4+4))
  const int qd = lane >> 4;        // quad
  const int cl = lane & 15;        // col/row-in-tile
  const int rb = wr * 16;          // wave's M-tile base row

  __shared__ __align__(16) char smem[S_TOT];
  ushort_t* Hc   = (ushort_t*)(smem + S_HC);   // [feat*72 + node]
  float*    Pf   = (float*)   (smem + S_R);    // 64x64 f32 (swizzled)
  ushort_t* Hr   = (ushort_t*)(smem + S_R);    // stride 136 (row-major)
  float*    part = (float*)   (smem + S_PART);
  float*    ns   = (float*)   (smem + S_NS);
  float*    nd   = (float*)   (smem + S_ND);
  float*    gp   = (float*)   (smem + S_GP);
  float*    ebw  = (float*)   (smem + S_EBW);
  float*    hc   = (float*)   (smem + S_HCC);
  int*      xs   = (int*)     (smem + S_XS);
  ushort_t* a1b  = Hc;                         // 64x136 rows

  // ---- P0: edge regs, pair regs, xs -> ns/nd tables, zero Pf/gp, consts ----
  unsigned er[2];
  #pragma unroll
  for (int i = 0; i < 2; ++i) {
    const int k = tid + 512*i;
    const int s = ei[gid*EPG + k] - nb;
    const int d = ei[E_TOT + gid*EPG + k] - nb;
    const int t = ea[gid*EPG + k];
    er[i] = (unsigned)(s | (d << 6) | (t << 12));
  }
  const int2 prr = *(const int2*)(nedg + 2*(gid*NEPG + (tid >> 1)));
  if (tid < NPG) {
    const int cat = x[nb + tid];
    xs[tid] = cat;
    ns[tid] = g_hs1[cat];
    nd[tid] = g_hd1[cat];
  }
  {
    float4* pz = (float4*)Pf;
    pz[tid]       = make_float4(0.f,0.f,0.f,0.f);
    pz[tid + 512] = make_float4(0.f,0.f,0.f,0.f);
  }
  if (tid < 128) gp[tid] = 0.f;
  if (tid < 256) ebw[tid] = (tid < 128) ? e_b1[tid] : e_w2[tid - 128];
  if (tid < 8) hc[tid] = (tid < 4) ? g_he1[tid] : g_he2[tid-4];
  __syncthreads();                                        // B1

  // ---- E1+G: layer-1 edge pass (atomics) overlapped with nt1->Hc gather ----
  // wave = 16-feat block, lane = node: LDS writes lane-consecutive.
  {
    const int f0 = wv * 16;
    const ushort_t* srcp = g_nt1 + xs[lane]*HID + f0;
    const bf16x8 t0 = ((const bf16x8*)srcp)[0];
    const bf16x8 t1 = ((const bf16x8*)srcp)[1];
    #pragma unroll
    for (int i = 0; i < 2; ++i) {
      const unsigned tp = er[i];
      const int s = tp & 63, d = (tp >> 6) & 63, t = tp >> 12;
      float l = ns[s] + nd[d] + hc[t];
      l = (l > 0.f) ? l : 0.2f * l;
      atomicAdd(&Pf[pf_idx(d, s)], __expf(l));
    }
    #pragma unroll
    for (int q = 0; q < 8; ++q) {
      Hc[(f0 +     q)*72 + lane] = (ushort_t)t0[q];
      Hc[(f0 + 8 + q)*72 + lane] = (ushort_t)t1[q];
    }
  }
  __syncthreads();                                        // B2

  // ---- agg1 preload: P frags (swizzled read, f32->bf16) + den rowsum ----
  bf16x8 pa0, pa1;
  float inv4[4];
  {
    const float* pr = Pf + (rb + cl)*64;
    const float4 v0 = *(const float4*)(pr + (((2*qd    ) ^ cl) << 2));
    const float4 v1 = *(const float4*)(pr + (((2*qd + 1) ^ cl) << 2));
    const float4 v2 = *(const float4*)(pr + (((2*qd + 8) ^ cl) << 2));
    const float4 v3 = *(const float4*)(pr + (((2*qd + 9) ^ cl) << 2));
    pa0 = pk8(v0, v1); pa1 = pk8(v2, v3);
    float den = v0.x+v0.y+v0.z+v0.w + v1.x+v1.y+v1.z+v1.w
              + v2.x+v2.y+v2.z+v2.w + v3.x+v3.y+v3.z+v3.w;
    den += __shfl_xor(den, 16, 64);
    den += __shfl_xor(den, 32, 64);
    #pragma unroll
    for (int r = 0; r < 4; ++r)
      inv4[r] = 1.f / (__shfl(den, qd*4 + r, 64) + 1e-16f);
  }
  if (tid < NPG) { ns[tid] = 0.f; nd[tid] = 0.f; }   // for P7 atomic accum
  __syncthreads();                                        // B3

  // ---- agg1: h1 = relu(inv*(P@h1pre) + c1_b) -> Hr (col-half per wave) ----
  {
    #pragma unroll
    for (int i = 0; i < 4; ++i) {
      const int ct = ch*4 + i;
      f32x4 acc = {0.f, 0.f, 0.f, 0.f};
      const bf16x8 b0 = *(const bf16x8*)(Hc + (ct*16+cl)*72 + qd*8);
      const bf16x8 b1 = *(const bf16x8*)(Hc + (ct*16+cl)*72 + 32 + qd*8);
      acc = __builtin_amdgcn_mfma_f32_16x16x32_bf16(pa0, b0, acc, 0, 0, 0);
      acc = __builtin_amdgcn_mfma_f32_16x16x32_bf16(pa1, b1, acc, 0, 0, 0);
      const int n = ct*16 + cl;
      const float bias = c1_b[n];
      #pragma unroll
      for (int r = 0; r < 4; ++r)
        Hr[(rb + qd*4 + r)*136 + n] = f2bf(fmaxf(fmaf(acc[r], inv4[r], bias), 0.f));
    }
  }
  __syncthreads();                                        // B4
  bf16x8 h1f[4];                     // full-width rows (cross-wave halves)
  #pragma unroll
  for (int ks = 0; ks < 4; ++ks)
    h1f[ks] = *(const bf16x8*)(Hr + (rb+cl)*136 + ks*32 + qd*8);
  __syncthreads();                                        // B4b

  // ---- P7: h2pre = h1 @ c2_w -> Hc + ns/nd (atomic); zero Pf ----
  {
    float4* pz = (float4*)Pf;
    pz[tid]       = make_float4(0.f,0.f,0.f,0.f);
    pz[tid + 512] = make_float4(0.f,0.f,0.f,0.f);
    float pns[4] = {0.f,0.f,0.f,0.f}, pnd[4] = {0.f,0.f,0.f,0.f};
    #pragma unroll
    for (int i = 0; i < 4; ++i) {
      const int ct = ch*4 + i;
      f32x4 acc = {0.f, 0.f, 0.f, 0.f};
      #pragma unroll
      for (int ks = 0; ks < 4; ++ks) {
        const bf16x8 b = *(const bf16x8*)(g_c2w + ((ct*4+ks)*64 + lane)*8);
        acc = __builtin_amdgcn_mfma_f32_16x16x32_bf16(h1f[ks], b, acc, 0, 0, 0);
      }
      const int n = ct*16 + cl;
      const float asv = c2_as[n], adv = c2_ad[n];
      #pragma unroll
      for (int r = 0; r < 4; ++r) {
        const float v = acc[r];
        Hc[n*72 + (rb + qd*4 + r)] = f2bf(v);
        pns[r] = fmaf(v, asv, pns[r]);
        pnd[r] = fmaf(v, adv, pnd[r]);
      }
    }
    #pragma unroll
    for (int r = 0; r < 4; ++r) {
      #pragma unroll
      for (int off = 1; off < 16; off <<= 1) {
        pns[r] += __shfl_xor(pns[r], off, 64);
        pnd[r] += __shfl_xor(pnd[r], off, 64);
      }
    }
    if (cl == 0) {
      #pragma unroll
      for (int r = 0; r < 4; ++r) {
        atomicAdd(&ns[rb + qd*4 + r], pns[r]);
        atomicAdd(&nd[rb + qd*4 + r], pnd[r]);
      }
    }
  }
  __syncthreads();                                        // B5

  // ---- edge pass 2 ----
  #pragma unroll
  for (int i = 0; i < 2; ++i) {
    const unsigned tp = er[i];
    const int s = tp & 63, d = (tp >> 6) & 63, t = tp >> 12;
    float l = ns[s] + nd[d] + hc[4 + t];
    l = (l > 0.f) ? l : 0.2f * l;
    atomicAdd(&Pf[pf_idx(d, s)], __expf(l));
  }
  __syncthreads();                                        // B6

  // ---- agg2 preload ----
  {
    const float* pr = Pf + (rb + cl)*64;
    const float4 v0 = *(const float4*)(pr + (((2*qd    ) ^ cl) << 2));
    const float4 v1 = *(const float4*)(pr + (((2*qd + 1) ^ cl) << 2));
    const float4 v2 = *(const float4*)(pr + (((2*qd + 8) ^ cl) << 2));
    const float4 v3 = *(const float4*)(pr + (((2*qd + 9) ^ cl) << 2));
    pa0 = pk8(v0, v1); pa1 = pk8(v2, v3);
    float den = v0.x+v0.y+v0.z+v0.w + v1.x+v1.y+v1.z+v1.w
              + v2.x+v2.y+v2.z+v2.w + v3.x+v3.y+v3.z+v3.w;
    den += __shfl_xor(den, 16, 64);
    den += __shfl_xor(den, 32, 64);
    #pragma unroll
    for (int r = 0; r < 4; ++r)
      inv4[r] = 1.f / (__shfl(den, qd*4 + r, 64) + 1e-16f);
  }
  __syncthreads();                                        // B7

  // ---- agg2: h2 = inv*(P@h2pre) + c2_b -> Hr + pooling ----
  {
    #pragma unroll
    for (int i = 0; i < 4; ++i) {
      const int ct = ch*4 + i;
      f32x4 acc = {0.f, 0.f, 0.f, 0.f};
      const bf16x8 b0 = *(const bf16x8*)(Hc + (ct*16+cl)*72 + qd*8);
      const bf16x8 b1 = *(const bf16x8*)(Hc + (ct*16+cl)*72 + 32 + qd*8);
      acc = __builtin_amdgcn_mfma_f32_16x16x32_bf16(pa0, b0, acc, 0, 0, 0);
      acc = __builtin_amdgcn_mfma_f32_16x16x32_bf16(pa1, b1, acc, 0, 0, 0);
      const int n = ct*16 + cl;
      const float bias = c2_b[n];
      float colsum = 0.f;
      #pragma unroll
      for (int r = 0; r < 4; ++r) {
        const float v = fmaf(acc[r], inv4[r], bias);
        Hr[(rb + qd*4 + r)*136 + n] = f2bf(v);
        colsum += v;
      }
      colsum += __shfl_xor(colsum, 16, 64);
      colsum += __shfl_xor(colsum, 32, 64);
      if (qd == 0) atomicAdd(&gp[n], colsum);
    }
  }
  __syncthreads();                                        // B8

  // ---- stop head partials (4 k-chunks of 32) + h2f hoist (rows full-width,
  //      cross-wave halves: B8 fences agg2 writes, B9 fences before u-write) --
  {
    const int j = tid & 127, c = tid >> 7;
    const float* wrp = g_sw1t + j*HID + c*32;
    const float* grp = gp + c*32;
    float p = 0.f;
    #pragma unroll
    for (int q = 0; q < 8; ++q) {
      const float4 w = ((const float4*)wrp)[q];
      const float4 g = ((const float4*)grp)[q];
      p = fmaf(w.x, g.x, p); p = fmaf(w.y, g.y, p);
      p = fmaf(w.z, g.z, p); p = fmaf(w.w, g.w, p);
    }
    part[tid] = p;
  }
  bf16x8 h2f[4];
  #pragma unroll
  for (int ks = 0; ks < 4; ++ks)
    h2f[ks] = *(const bf16x8*)(Hr + (rb+cl)*136 + ks*32 + qd*8);
  __syncthreads();                                        // B9

  // ---- post-B9: stop reduce (wave 0), fused addnode/addedge staging ----
  if (tid < 64) {
    const float d0 = part[tid]    + part[tid+128] + part[tid+256] + part[tid+384];
    const float d1 = part[tid+64] + part[tid+192] + part[tid+320] + part[tid+448];
    const float z0 = fmaxf(d0 + s_b1[tid], 0.f);
    const float z1 = fmaxf(d1 + s_b1[tid+64], 0.f);
    float p = fmaf(z0, s_w2[tid], z1 * s_w2[tid+64]);
    #pragma unroll
    for (int off = 32; off > 0; off >>= 1) p += __shfl_down(p, off, 64);
    if (tid == 0) out[(size_t)gid*OUT_PG] = p + s_b2[0];
  }

  // fused: a1 = relu(h2@n_w1+n_b1) -> a1b(Hc);  u = h2@e_w1 -> Hr
  {
    #pragma unroll
    for (int i = 0; i < 4; ++i) {
      const int ct = ch*4 + i;
      f32x4 an  = {0.f, 0.f, 0.f, 0.f};
      f32x4 ae2 = {0.f, 0.f, 0.f, 0.f};
      #pragma unroll
      for (int ks = 0; ks < 4; ++ks) {
        const bf16x8 bn = *(const bf16x8*)(g_nw1 + ((ct*4+ks)*64 + lane)*8);
        const bf16x8 be = *(const bf16x8*)(g_ew1 + ((ct*4+ks)*64 + lane)*8);
        an  = __builtin_amdgcn_mfma_f32_16x16x32_bf16(h2f[ks], bn, an, 0, 0, 0);
        ae2 = __builtin_amdgcn_mfma_f32_16x16x32_bf16(h2f[ks], be, ae2, 0, 0, 0);
      }
      const int n = ct*16 + cl;
      const float bias = n_b1[n];
      #pragma unroll
      for (int r = 0; r < 4; ++r) {
        a1b[(rb + qd*4 + r)*136 + n] = f2bf(fmaxf(an[r] + bias, 0.f));
        Hr[(rb + qd*4 + r)*136 + n] = f2bf(ae2[r]);
      }
    }
  }
  __syncthreads();                                        // B9b

  // addnode head: out = a1 @ n_w2p + n_b2 (full-width a1b rows)
  {
    bf16x8 af[4];
    #pragma unroll
    for (int ks = 0; ks < 4; ++ks)
      af[ks] = *(const bf16x8*)(a1b + (rb+cl)*136 + ks*32 + qd*8);
    float* ob = out + (size_t)gid*OUT_PG + 1;
    #pragma unroll
    for (int i = 0; i < 4; ++i) {
      const int ct = ch*4 + i;
      if (ct < 7) {
        f32x4 acc = {0.f, 0.f, 0.f, 0.f};
        #pragma unroll
        for (int ks = 0; ks < 4; ++ks) {
          const bf16x8 b = *(const bf16x8*)(g_nw2 + ((ct*4+ks)*64 + lane)*8);
          acc = __builtin_amdgcn_mfma_f32_16x16x32_bf16(af[ks], b, acc, 0, 0, 0);
        }
        const int o = ct*16 + cl;
        if (o < NOUT) {
          const float b2 = n_b2[o];
          #pragma unroll
          for (int r = 0; r < 4; ++r)
            ob[(size_t)(rb + qd*4 + r)*NOUT + o] = acc[r] + b2;
        }
      }
    }
  }
  __syncthreads();                                        // B10

  // ---- addedge pairs (u in Hr region): 2 lanes per pair, 64 feats each ----
  {
    const int pi = tid >> 1, hf = tid & 1;
    const ushort_t* ui = Hr + (prr.x - nb)*136 + hf*64;
    const ushort_t* uj = Hr + (prr.y - nb)*136 + hf*64;
    float ssum = 0.f;
    #pragma unroll
    for (int q8 = 0; q8 < 8; ++q8) {
      const bf16x8 va = *(const bf16x8*)(ui + q8*8);
      const bf16x8 vb = *(const bf16x8*)(uj + q8*8);
      #pragma unroll
      for (int j = 0; j < 8; ++j) {
        const int c = hf*64 + q8*8 + j;
        float v = bf2f((ushort_t)va[j]) + bf2f((ushort_t)vb[j]) + ebw[c];
        v = fmaxf(v, 0.f);
        ssum = fmaf(v, ebw[128 + c], ssum);
      }
    }
    ssum += __shfl_xor(ssum, 1, 64);
    if (hf == 0)
      out[(size_t)gid*OUT_PG + 1 + NPG*NOUT + pi] = ssum + e_b2[0];
  }
}

// ---------------------------------------------------------------------------
extern "C" void kernel_launch(void* const* d_in, const int* in_sizes, int n_in,
                              void* d_out, int out_size, void* d_ws, size_t ws_size,
                              hipStream_t stream) {
  const float* node_tab = (const float*)d_in[0];
  const float* edge_tab = (const float*)d_in[1];
  const float* c1_w  = (const float*)d_in[2];
  const float* c1_we = (const float*)d_in[3];
  const float* c1_as = (const float*)d_in[4];
  const float* c1_ad = (const float*)d_in[5];
  const float* c1_ae = (const float*)d_in[6];
  const float* c1_b  = (const float*)d_in[7];
  const float* c2_w  = (const float*)d_in[8];
  const float* c2_we = (const float*)d_in[9];
  const float* c2_as = (const float*)d_in[10];
  const float* c2_ad = (const float*)d_in[11];
  const float* c2_ae = (const float*)d_in[12];
  const float* c2_b  = (const float*)d_in[13];
  const float* s_w1  = (const float*)d_in[14];
  const float* s_b1  = (const float*)d_in[15];
  const float* s_w2  = (const float*)d_in[16];
  const float* s_b2  = (const float*)d_in[17];
  const float* n_w1  = (const float*)d_in[18];
  const float* n_b1  = (const float*)d_in[19];
  const float* n_w2  = (const float*)d_in[20];
  const float* n_b2  = (const float*)d_in[21];
  const float* e_w1  = (const float*)d_in[22];
  const float* e_b1  = (const float*)d_in[23];
  const float* e_w2  = (const float*)d_in[24];
  const float* e_b2  = (const float*)d_in[25];
  const int* x    = (const int*)d_in[26];
  const int* ei   = (const int*)d_in[27];
  const int* ea   = (const int*)d_in[28];
  const int* nedg = (const int*)d_in[29];
  float* out = (float*)d_out;

  prep_kernel<<<dim3(91), dim3(256), 0, stream>>>(
      node_tab, edge_tab, c1_w, c1_we, c1_as, c1_ad, c1_ae,
      c2_w, c2_we, c2_ae, s_w1, n_w1, n_w2, e_w1);

  graph_kernel<<<dim3(B_GR), dim3(512), 0, stream>>>(
      c1_b, c2_as, c2_ad, c2_b, s_b1, s_w2, s_b2,
      n_b1, n_b2, e_b1, e_w2, e_b2, x, ei, ea, nedg, out);
}